// Round 7
// baseline (209.302 us; speedup 1.0000x reference)
//
#include <hip/hip_runtime.h>
#include <hip/hip_bf16.h>

// TopPool: out[b,c,h,w] = max_{h'>=h} x[b,c,h',w]  (reverse cummax over axis 2)
// x shape (32, 256, 128, 128) fp32, w innermost. Compulsory 0.537+0.537 GB.
// R7 = R4 config (float4 granule, U=8, 2-deep prefetch pipeline, nt loads)
// with ONE change: stores are plain (no nt). Theory: nt on the store stream
// bypasses/weakens L2 write-combining; the harness's fill kernels (no nt)
// sustain 6.4-6.8 TB/s write-only while we see ~5.5 TB/s mixed. A/B test.
// (R5 ascending-burst reorder and R6 float2/full-occupancy both regressed;
// latency cover and burst order are ruled out.)

#define H 128
#define W4 32   // 128 floats / 4 per float4
#define U 8     // h-steps per batch
#define NB (H / U)  // 16 batches

typedef float f32x4 __attribute__((ext_vector_type(4)));

__device__ __forceinline__ f32x4 fmax4(f32x4 a, f32x4 b) {
    f32x4 r;
    r.x = fmaxf(a.x, b.x);
    r.y = fmaxf(a.y, b.y);
    r.z = fmaxf(a.z, b.z);
    r.w = fmaxf(a.w, b.w);
    return r;
}

__global__ __launch_bounds__(256) void toppool_kernel(const f32x4* __restrict__ x,
                                                      f32x4* __restrict__ out) {
    const int tid   = blockIdx.x * blockDim.x + threadIdx.x;   // 0 .. 262143
    const int w4    = tid & (W4 - 1);
    const int plane = tid >> 5;                                 // b*C + c

    const size_t base = (size_t)plane * H * W4 + w4;
    const f32x4* xp = x + base;
    f32x4* op = out + base;

    f32x4 cur[U], nxt[U];

    // prologue: load h = 127..120
    #pragma unroll
    for (int i = 0; i < U; ++i)
        cur[i] = __builtin_nontemporal_load(&xp[(H - 1 - i) * W4]);

    f32x4 m;
    m.x = -__builtin_huge_valf();
    m.y = -__builtin_huge_valf();
    m.z = -__builtin_huge_valf();
    m.w = -__builtin_huge_valf();

    // main: batches 0 .. NB-2, each prefetches the following batch first
    for (int b = 0; b < NB - 1; ++b) {
        const int hbase = H - 1 - b * U;
        // issue next batch's loads (independent of the fmax chain)
        #pragma unroll
        for (int i = 0; i < U; ++i)
            nxt[i] = __builtin_nontemporal_load(&xp[(hbase - U - i) * W4]);
        // compute + store current batch (plain stores — let L2 write-combine)
        #pragma unroll
        for (int i = 0; i < U; ++i) {
            m = fmax4(m, cur[i]);
            op[(hbase - i) * W4] = m;
        }
        #pragma unroll
        for (int i = 0; i < U; ++i) cur[i] = nxt[i];
    }

    // epilogue: last batch (h = 7..0)
    #pragma unroll
    for (int i = 0; i < U; ++i) {
        m = fmax4(m, cur[i]);
        op[(U - 1 - i) * W4] = m;
    }
}

extern "C" void kernel_launch(void* const* d_in, const int* in_sizes, int n_in,
                              void* d_out, int out_size, void* d_ws, size_t ws_size,
                              hipStream_t stream) {
    const f32x4* x = (const f32x4*)d_in[0];
    f32x4* out = (f32x4*)d_out;

    const int total = 32 * 256 * W4;   // 262144 threads
    const int block = 256;
    const int grid = total / block;    // 1024
    toppool_kernel<<<grid, block, 0, stream>>>(x, out);
}

// Round 10
// 205.145 us; speedup vs baseline: 1.0203x; 1.0203x over previous
//
#include <hip/hip_runtime.h>
#include <hip/hip_bf16.h>

// TopPool: out[b,c,h,w] = max_{h'>=h} x[b,c,h',w]  (reverse cummax over axis 2)
// x shape (32, 256, 128, 128) fp32, w innermost. Compulsory 0.537+0.537 GB.
// FINAL (= R4, best measured 193.7 us, 5.54 TB/s eff = 88% of copy ubench):
//   - one thread per (plane, float4-column); 64-lane wave = two contiguous
//     512 B segments per step, fully coalesced 16 B/lane.
//   - nontemporal loads AND stores (A/B'd: removing either regresses).
//   - 2-deep software pipeline, U=8: next batch's 8 loads issued before the
//     current batch's fmax+store chain -> 8 KB/wave always in flight.
// Ruled out by A/B: ascending-burst reorder (R5), float2 + full occupancy
// (R6), plain stores (R7), shallower unroll (R1/R3).

#define H 128
#define W4 32   // 128 floats / 4 per float4
#define U 8     // h-steps per batch
#define NB (H / U)  // 16 batches

typedef float f32x4 __attribute__((ext_vector_type(4)));

__device__ __forceinline__ f32x4 fmax4(f32x4 a, f32x4 b) {
    f32x4 r;
    r.x = fmaxf(a.x, b.x);
    r.y = fmaxf(a.y, b.y);
    r.z = fmaxf(a.z, b.z);
    r.w = fmaxf(a.w, b.w);
    return r;
}

__global__ __launch_bounds__(256) void toppool_kernel(const f32x4* __restrict__ x,
                                                      f32x4* __restrict__ out) {
    const int tid   = blockIdx.x * blockDim.x + threadIdx.x;   // 0 .. 262143
    const int w4    = tid & (W4 - 1);
    const int plane = tid >> 5;                                 // b*C + c

    const size_t base = (size_t)plane * H * W4 + w4;
    const f32x4* xp = x + base;
    f32x4* op = out + base;

    f32x4 cur[U], nxt[U];

    // prologue: load h = 127..120
    #pragma unroll
    for (int i = 0; i < U; ++i)
        cur[i] = __builtin_nontemporal_load(&xp[(H - 1 - i) * W4]);

    f32x4 m;
    m.x = -__builtin_huge_valf();
    m.y = -__builtin_huge_valf();
    m.z = -__builtin_huge_valf();
    m.w = -__builtin_huge_valf();

    // main: batches 0 .. NB-2, each prefetches the following batch first
    for (int b = 0; b < NB - 1; ++b) {
        const int hbase = H - 1 - b * U;
        // issue next batch's loads (independent of the fmax chain)
        #pragma unroll
        for (int i = 0; i < U; ++i)
            nxt[i] = __builtin_nontemporal_load(&xp[(hbase - U - i) * W4]);
        // compute + store current batch
        #pragma unroll
        for (int i = 0; i < U; ++i) {
            m = fmax4(m, cur[i]);
            __builtin_nontemporal_store(m, &op[(hbase - i) * W4]);
        }
        #pragma unroll
        for (int i = 0; i < U; ++i) cur[i] = nxt[i];
    }

    // epilogue: last batch (h = 7..0)
    #pragma unroll
    for (int i = 0; i < U; ++i) {
        m = fmax4(m, cur[i]);
        __builtin_nontemporal_store(m, &op[(U - 1 - i) * W4]);
    }
}

extern "C" void kernel_launch(void* const* d_in, const int* in_sizes, int n_in,
                              void* d_out, int out_size, void* d_ws, size_t ws_size,
                              hipStream_t stream) {
    const f32x4* x = (const f32x4*)d_in[0];
    f32x4* out = (f32x4*)d_out;

    const int total = 32 * 256 * W4;   // 262144 threads
    const int block = 256;
    const int grid = total / block;    // 1024
    toppool_kernel<<<grid, block, 0, stream>>>(x, out);
}